// Round 10
// baseline (187.403 us; speedup 1.0000x reference)
//
#include <hip/hip_runtime.h>

#define N_NODES 50000
#define N_EDGES 800000
#define D 64
#define NBUCKETS 3125         // dst>>4, 0..3124
#define NPB 16                // nodes per bucket
#define BCAP 512              // per-bucket capacity (Poisson(256), 16sigma)
#define SBLOCKS 256           // scatter blocks
#define CHUNK (N_EDGES / SBLOCKS)   // 3125
#define MB ((N_NODES + 63) / 64)    // 782 gemm tiles

typedef short bf16x8 __attribute__((ext_vector_type(8)));   // 8 bf16 = 4 VGPRs
typedef float f32x4  __attribute__((ext_vector_type(4)));   // MFMA accumulator

// bf16 helpers (RNE), bit-level.
__device__ __forceinline__ unsigned short f2bf(float f) {
    unsigned u = __float_as_uint(f);
    return (unsigned short)((u + 0x7fffu + ((u >> 16) & 1u)) >> 16);
}
__device__ __forceinline__ float bflo(unsigned u) {
    return __uint_as_float(u << 16);
}
__device__ __forceinline__ float bfhi(unsigned u) {
    return __uint_as_float(u & 0xffff0000u);
}

// ---------- prep: zero cursors + build bf16 W^T for all 4 weights -----------
// blocks 0..3: W^T build; blocks 4..11: zero cursorPad (3125*16 ints).
__global__ void __launch_bounds__(256) prep_kernel(
    const float* __restrict__ W1r, const float* __restrict__ W1n,
    const float* __restrict__ W2r, const float* __restrict__ W2n,
    int* __restrict__ cursorPad, unsigned short* __restrict__ wt) {
    int t = threadIdx.x;
    if (blockIdx.x >= 4) {
        int lo = (blockIdx.x - 4) * (NBUCKETS * 16 / 8);
        int hi = lo + (NBUCKETS * 16 / 8);
        for (int i = lo + t; i < hi; i += 256) cursorPad[i] = 0;
        return;
    }
    const float* Wsrc = blockIdx.x == 0 ? W1r : blockIdx.x == 1 ? W1n
                      : blockIdx.x == 2 ? W2r : W2n;
    unsigned short* dstw = wt + blockIdx.x * D * D;
    for (int i = t; i < D * D; i += 256) {
        int k = i >> 6, c = i & 63;           // coalesced read of W[k][c]
        dstw[c * D + k] = f2bf(Wsrc[i]);      // transposed bf16 store
    }
}

// ---------- scatter body (verified two-pass form; 16-node buckets) ----------
// LDS: hist@0 (3125 ints), curs@12500, pk@25000 (3125 ints), bk@37500 (u16).
__device__ __forceinline__ void scatter_body(
    const int* __restrict__ src, const int* __restrict__ dst,
    int* __restrict__ cursorPad, int* __restrict__ staged,
    char* smem, int bid, int t) {
    int* hist = (int*)smem;
    int* curs = (int*)(smem + 12500);
    int* pk   = (int*)(smem + 25000);
    unsigned short* bk = (unsigned short*)(smem + 37500);
    for (int i = t; i < NBUCKETS; i += 256) hist[i] = 0;
    __syncthreads();
    int lo = bid * CHUNK;
    for (int i = t; i < CHUNK; i += 256) {
        int d = dst[lo + i];
        int s = src[lo + i];
        pk[i] = (s << 4) | (d & 15);
        bk[i] = (unsigned short)(d >> 4);
        atomicAdd(&hist[d >> 4], 1);
    }
    __syncthreads();
    for (int k = t; k < NBUCKETS; k += 256)
        if (hist[k] > 0)
            curs[k] = k * BCAP + atomicAdd(&cursorPad[k * 16], hist[k]);
    __syncthreads();
    for (int i = t; i < CHUNK; i += 256) {
        int b = bk[i];
        int pos = atomicAdd(&curs[b], 1);
        staged[pos] = pk[i];
    }
}

// ---------- MFMA dual GEMM body (verified R7 form) --------------------------
template<int XBF>
__device__ __forceinline__ void gemm_mfma_body(
    const float* __restrict__ Xf, const unsigned short* __restrict__ Xb,
    const unsigned short* __restrict__ Wtr, const unsigned short* __restrict__ Wtn,
    float* __restrict__ outR, unsigned short* __restrict__ outN,
    int node0, int tid) {
    int wave = tid >> 6, lane = tid & 63;
    int rbase = node0 + wave * 16;            // 16 nodes per wave
    int rrow  = lane & 15;
    int kg    = lane >> 4;                    // k-chunk selector (0..3)
    int row   = min(rbase + rrow, N_NODES - 1);

    bf16x8 a0, a1;                            // k 0..31 / 32..63
    if (XBF) {
        a0 = *(const bf16x8*)(Xb + (size_t)row * D + kg * 8);
        a1 = *(const bf16x8*)(Xb + (size_t)row * D + 32 + kg * 8);
    } else {
        const float* xp = Xf + (size_t)row * D + kg * 8;
#pragma unroll
        for (int j = 0; j < 8; j++) a0[j] = (short)f2bf(xp[j]);
#pragma unroll
        for (int j = 0; j < 8; j++) a1[j] = (short)f2bf(xp[32 + j]);
    }

    f32x4 accR[4], accN[4];
#pragma unroll
    for (int t = 0; t < 4; t++) {
        accR[t][0] = 0.f; accR[t][1] = 0.f; accR[t][2] = 0.f; accR[t][3] = 0.f;
        accN[t][0] = 0.f; accN[t][1] = 0.f; accN[t][2] = 0.f; accN[t][3] = 0.f;
    }

#pragma unroll
    for (int t = 0; t < 4; t++) {
        int c = t * 16 + rrow;                // W^T row = W column
        bf16x8 br0 = *(const bf16x8*)(Wtr + c * D + kg * 8);
        bf16x8 br1 = *(const bf16x8*)(Wtr + c * D + 32 + kg * 8);
        bf16x8 bn0 = *(const bf16x8*)(Wtn + c * D + kg * 8);
        bf16x8 bn1 = *(const bf16x8*)(Wtn + c * D + 32 + kg * 8);
        accR[t] = __builtin_amdgcn_mfma_f32_16x16x32_bf16(a0, br0, accR[t], 0, 0, 0);
        accR[t] = __builtin_amdgcn_mfma_f32_16x16x32_bf16(a1, br1, accR[t], 0, 0, 0);
        accN[t] = __builtin_amdgcn_mfma_f32_16x16x32_bf16(a0, bn0, accN[t], 0, 0, 0);
        accN[t] = __builtin_amdgcn_mfma_f32_16x16x32_bf16(a1, bn1, accN[t], 0, 0, 0);
    }

#pragma unroll
    for (int t = 0; t < 4; t++) {
#pragma unroll
        for (int i = 0; i < 4; i++) {
            int n = rbase + kg * 4 + i;       // D row
            if (n < N_NODES) {
                int c = t * 16 + rrow;        // D col
                outR[(size_t)n * D + c] = accR[t][i];
                outN[(size_t)n * D + c] = f2bf(accN[t][i]);
            }
        }
    }
}

// ---------- merged scatter + layer-1 GEMM (block-specialized) ---------------
__global__ void __launch_bounds__(256) scatter_gemm1(
    const int* __restrict__ src, const int* __restrict__ dst,
    int* __restrict__ cursorPad, int* __restrict__ staged,
    const float* __restrict__ X, const unsigned short* __restrict__ wt,
    float* __restrict__ xr, unsigned short* __restrict__ xn) {
    __shared__ char smem[43776];              // scatter role only
    if (blockIdx.x < SBLOCKS) {
        scatter_body(src, dst, cursorPad, staged, smem, blockIdx.x, threadIdx.x);
    } else {
        gemm_mfma_body<0>(X, (const unsigned short*)0,
                          wt + 0 * D * D, wt + 1 * D * D,
                          xr, xn, (blockIdx.x - SBLOCKS) * 64, threadIdx.x);
    }
}

// ---------- fused CSR-build + layer-1 gather + layer-2 GEMM -----------------
// One block per 16-node bucket (3125 blocks, 512 threads).
// Phase 0: build this bucket's CSR in LDS from staged; write csr/startEnd
//          to global for gather2.
// Phase A: R8-verified 2-node-per-wave gather, indices from LDS lcsr.
// Phase B: dual MFMA GEMM over the 16 h rows (R9-verified form).
__global__ void __launch_bounds__(512) gather1_gemm2(
    const int* __restrict__ cursorPad, const int* __restrict__ staged,
    int* __restrict__ csr, int* __restrict__ startEnd,
    const unsigned short* __restrict__ Gsrc, const float* __restrict__ Root,
    const float* __restrict__ bias, const unsigned short* __restrict__ wt,
    float* __restrict__ hr, unsigned short* __restrict__ hn) {
    __shared__ int sdeg[NPB];
    __shared__ int sstart[NPB];
    __shared__ int scurs[NPB];
    __shared__ int lcsr[BCAP];                // 2 KB
    __shared__ unsigned short hlds[16][72];   // h tile, pitch 72
    int k = blockIdx.x;
    int tid = threadIdx.x;
    int gbase = k * BCAP;
    int cnt = cursorPad[k * 16];

    if (tid < NPB) sdeg[tid] = 0;
    __syncthreads();
    for (int i = tid; i < cnt; i += 512)
        atomicAdd(&sdeg[staged[gbase + i] & 15], 1);
    __syncthreads();
    if (tid == 0) {
        int acc = 0;
#pragma unroll
        for (int j = 0; j < NPB; j++) { sstart[j] = acc; scurs[j] = acc; acc += sdeg[j]; }
    }
    __syncthreads();
    for (int i = tid; i < cnt; i += 512) {
        int e = staged[gbase + i];
        int pos = atomicAdd(&scurs[e & 15], 1);
        lcsr[pos] = e >> 4;
    }
    __syncthreads();
    // publish for gather2 (independent of phase A)
    for (int i = tid; i < cnt; i += 512) csr[gbase + i] = lcsr[i];
    if (tid < NPB) {
        int2 se; se.x = gbase + sstart[tid]; se.y = gbase + sstart[tid] + sdeg[tid];
        ((int2*)startEnd)[k * NPB + tid] = se;
    }

    // ---- phase A: gather (2 nodes per wave, LDS indices)
    int wave = tid >> 6, lane = tid & 63;
    int cA = wave * 2, cB = cA + 1;
    int n0 = k * NPB;
    int nA = n0 + cA, nB = n0 + cB;
    int sub = lane >> 3, fq = lane & 7;
    int jbA = sstart[cA], jeA = jbA + sdeg[cA];
    int jbB = sstart[cB], jeB = jbB + sdeg[cB];

    float4 xA0, xA1, xB0, xB1, b0, b1;
    if (sub == 0) {
        const float* rpA = Root + (size_t)nA * D + fq * 8;
        const float* rpB = Root + (size_t)nB * D + fq * 8;
        xA0 = *(const float4*)rpA; xA1 = *(const float4*)(rpA + 4);
        xB0 = *(const float4*)rpB; xB1 = *(const float4*)(rpB + 4);
        b0 = ((const float4*)bias)[fq * 2];
        b1 = ((const float4*)bias)[fq * 2 + 1];
    }

    float aA0=0.f,aA1=0.f,aA2=0.f,aA3=0.f,aA4=0.f,aA5=0.f,aA6=0.f,aA7=0.f;
    float aB0=0.f,aB1=0.f,aB2=0.f,aB3=0.f,aB4=0.f,aB5=0.f,aB6=0.f,aB7=0.f;

    while (jbA < jeA || jbB < jeB) {          // wave-uniform
        int pA = 0, pB = 0, mA = 0, mB = 0;
        if (jbA < jeA) {
            int idx = jbA + lane;
            pA = lcsr[idx < jeA ? idx : (jeA - 1)];
            mA = min(64, jeA - jbA);
        }
        if (jbB < jeB) {
            int idx = jbB + lane;
            pB = lcsr[idx < jeB ? idx : (jeB - 1)];
            mB = min(64, jeB - jbB);
        }
        if (mA) {
            int b = 0;
            for (; b + 16 <= mA; b += 16) {
                int i0 = __shfl(pA, b + sub, 64);
                int i1 = __shfl(pA, b + 8 + sub, 64);
                uint4 u0 = *(const uint4*)(Gsrc + i0 * D + fq * 8);
                uint4 u1 = *(const uint4*)(Gsrc + i1 * D + fq * 8);
                aA0 += bflo(u0.x) + bflo(u1.x);  aA1 += bfhi(u0.x) + bfhi(u1.x);
                aA2 += bflo(u0.y) + bflo(u1.y);  aA3 += bfhi(u0.y) + bfhi(u1.y);
                aA4 += bflo(u0.z) + bflo(u1.z);  aA5 += bfhi(u0.z) + bfhi(u1.z);
                aA6 += bflo(u0.w) + bflo(u1.w);  aA7 += bfhi(u0.w) + bfhi(u1.w);
            }
            for (; b < mA; b += 8) {
                int sidx = b + sub;
                int scl = sidx < mA ? sidx : (mA - 1);
                int i0 = __shfl(pA, scl, 64);
                if (sidx < mA) {
                    uint4 u = *(const uint4*)(Gsrc + i0 * D + fq * 8);
                    aA0 += bflo(u.x); aA1 += bfhi(u.x);
                    aA2 += bflo(u.y); aA3 += bfhi(u.y);
                    aA4 += bflo(u.z); aA5 += bfhi(u.z);
                    aA6 += bflo(u.w); aA7 += bfhi(u.w);
                }
            }
        }
        if (mB) {
            int b = 0;
            for (; b + 16 <= mB; b += 16) {
                int i0 = __shfl(pB, b + sub, 64);
                int i1 = __shfl(pB, b + 8 + sub, 64);
                uint4 u0 = *(const uint4*)(Gsrc + i0 * D + fq * 8);
                uint4 u1 = *(const uint4*)(Gsrc + i1 * D + fq * 8);
                aB0 += bflo(u0.x) + bflo(u1.x);  aB1 += bfhi(u0.x) + bfhi(u1.x);
                aB2 += bflo(u0.y) + bflo(u1.y);  aB3 += bfhi(u0.y) + bfhi(u1.y);
                aB4 += bflo(u0.z) + bflo(u1.z);  aB5 += bfhi(u0.z) + bfhi(u1.z);
                aB6 += bflo(u0.w) + bflo(u1.w);  aB7 += bfhi(u0.w) + bfhi(u1.w);
            }
            for (; b < mB; b += 8) {
                int sidx = b + sub;
                int scl = sidx < mB ? sidx : (mB - 1);
                int i0 = __shfl(pB, scl, 64);
                if (sidx < mB) {
                    uint4 u = *(const uint4*)(Gsrc + i0 * D + fq * 8);
                    aB0 += bflo(u.x); aB1 += bfhi(u.x);
                    aB2 += bflo(u.y); aB3 += bfhi(u.y);
                    aB4 += bflo(u.z); aB5 += bfhi(u.z);
                    aB6 += bflo(u.w); aB7 += bfhi(u.w);
                }
            }
        }
        jbA += 64; jbB += 64;
    }

#pragma unroll
    for (int mk = 8; mk <= 32; mk <<= 1) {
        aA0 += __shfl_xor(aA0, mk, 64); aA1 += __shfl_xor(aA1, mk, 64);
        aA2 += __shfl_xor(aA2, mk, 64); aA3 += __shfl_xor(aA3, mk, 64);
        aA4 += __shfl_xor(aA4, mk, 64); aA5 += __shfl_xor(aA5, mk, 64);
        aA6 += __shfl_xor(aA6, mk, 64); aA7 += __shfl_xor(aA7, mk, 64);
        aB0 += __shfl_xor(aB0, mk, 64); aB1 += __shfl_xor(aB1, mk, 64);
        aB2 += __shfl_xor(aB2, mk, 64); aB3 += __shfl_xor(aB3, mk, 64);
        aB4 += __shfl_xor(aB4, mk, 64); aB5 += __shfl_xor(aB5, mk, 64);
        aB6 += __shfl_xor(aB6, mk, 64); aB7 += __shfl_xor(aB7, mk, 64);
    }
    if (sub == 0) {
        float r0 = fmaxf(aA0 + xA0.x + b0.x, 0.f), r1 = fmaxf(aA1 + xA0.y + b0.y, 0.f);
        float r2 = fmaxf(aA2 + xA0.z + b0.z, 0.f), r3 = fmaxf(aA3 + xA0.w + b0.w, 0.f);
        float r4 = fmaxf(aA4 + xA1.x + b1.x, 0.f), r5 = fmaxf(aA5 + xA1.y + b1.y, 0.f);
        float r6 = fmaxf(aA6 + xA1.z + b1.z, 0.f), r7 = fmaxf(aA7 + xA1.w + b1.w, 0.f);
        float s0 = fmaxf(aB0 + xB0.x + b0.x, 0.f), s1 = fmaxf(aB1 + xB0.y + b0.y, 0.f);
        float s2 = fmaxf(aB2 + xB0.z + b0.z, 0.f), s3 = fmaxf(aB3 + xB0.w + b0.w, 0.f);
        float s4 = fmaxf(aB4 + xB1.x + b1.x, 0.f), s5 = fmaxf(aB5 + xB1.y + b1.y, 0.f);
        float s6 = fmaxf(aB6 + xB1.z + b1.z, 0.f), s7 = fmaxf(aB7 + xB1.w + b1.w, 0.f);
        uint4 u;
        u.x = (unsigned)f2bf(r0) | ((unsigned)f2bf(r1) << 16);
        u.y = (unsigned)f2bf(r2) | ((unsigned)f2bf(r3) << 16);
        u.z = (unsigned)f2bf(r4) | ((unsigned)f2bf(r5) << 16);
        u.w = (unsigned)f2bf(r6) | ((unsigned)f2bf(r7) << 16);
        *(uint4*)&hlds[cA][fq * 8] = u;
        u.x = (unsigned)f2bf(s0) | ((unsigned)f2bf(s1) << 16);
        u.y = (unsigned)f2bf(s2) | ((unsigned)f2bf(s3) << 16);
        u.z = (unsigned)f2bf(s4) | ((unsigned)f2bf(s5) << 16);
        u.w = (unsigned)f2bf(s6) | ((unsigned)f2bf(s7) << 16);
        *(uint4*)&hlds[cB][fq * 8] = u;
    }
    __syncthreads();

    // ---- phase B: dual GEMM over the block's 16 h rows
    int t4   = wave >> 1;                     // column tile 0..3
    int kind = wave & 1;                      // 0 -> hr (fp32), 1 -> hn (bf16)
    int rrow = lane & 15;
    int kg   = lane >> 4;
    bf16x8 a0 = *(const bf16x8*)&hlds[rrow][kg * 8];
    bf16x8 a1 = *(const bf16x8*)&hlds[rrow][32 + kg * 8];
    const unsigned short* Wt = wt + (2 + kind) * D * D;
    int c = t4 * 16 + rrow;
    bf16x8 bw0 = *(const bf16x8*)(Wt + c * D + kg * 8);
    bf16x8 bw1 = *(const bf16x8*)(Wt + c * D + 32 + kg * 8);
    f32x4 acc;
    acc[0] = 0.f; acc[1] = 0.f; acc[2] = 0.f; acc[3] = 0.f;
    acc = __builtin_amdgcn_mfma_f32_16x16x32_bf16(a0, bw0, acc, 0, 0, 0);
    acc = __builtin_amdgcn_mfma_f32_16x16x32_bf16(a1, bw1, acc, 0, 0, 0);
    if (kind == 0) {
#pragma unroll
        for (int i = 0; i < 4; i++)
            hr[(size_t)(n0 + kg * 4 + i) * D + c] = acc[i];
    } else {
#pragma unroll
        for (int i = 0; i < 4; i++)
            hn[(size_t)(n0 + kg * 4 + i) * D + c] = f2bf(acc[i]);
    }
}

// ---------- Gather 2 (verified R8 2-node form) + final epilogue -------------
__global__ void __launch_bounds__(256) gather2_out(
    const unsigned short* __restrict__ Gsrc, const float* __restrict__ Root,
    const float* __restrict__ bias,
    const int* __restrict__ startEnd, const int* __restrict__ csr,
    float* __restrict__ outF) {
    int tid = threadIdx.x;
    int wave = tid >> 6, lane = tid & 63;
    int nA = blockIdx.x * 8 + wave * 2;
    int nB = nA + 1;
    int sub = lane >> 3, fq = lane & 7;

    int4 se = *(const int4*)(startEnd + nA * 2);
    int jbA = se.x, jeA = se.y, jbB = se.z, jeB = se.w;

    float4 xA0, xA1, xB0, xB1, b0, b1;
    if (sub == 0) {
        const float* rpA = Root + (size_t)nA * D + fq * 8;
        const float* rpB = Root + (size_t)nB * D + fq * 8;
        xA0 = *(const float4*)rpA; xA1 = *(const float4*)(rpA + 4);
        xB0 = *(const float4*)rpB; xB1 = *(const float4*)(rpB + 4);
        b0 = ((const float4*)bias)[fq * 2];
        b1 = ((const float4*)bias)[fq * 2 + 1];
    }

    float aA0=0.f,aA1=0.f,aA2=0.f,aA3=0.f,aA4=0.f,aA5=0.f,aA6=0.f,aA7=0.f;
    float aB0=0.f,aB1=0.f,aB2=0.f,aB3=0.f,aB4=0.f,aB5=0.f,aB6=0.f,aB7=0.f;

    while (jbA < jeA || jbB < jeB) {
        int pA = 0, pB = 0, mA = 0, mB = 0;
        if (jbA < jeA) {
            int idx = jbA + lane;
            pA = csr[idx < jeA ? idx : (jeA - 1)];
            mA = min(64, jeA - jbA);
        }
        if (jbB < jeB) {
            int idx = jbB + lane;
            pB = csr[idx < jeB ? idx : (jeB - 1)];
            mB = min(64, jeB - jbB);
        }
        if (mA) {
            int b = 0;
            for (; b + 16 <= mA; b += 16) {
                int i0 = __shfl(pA, b + sub, 64);
                int i1 = __shfl(pA, b + 8 + sub, 64);
                uint4 u0 = *(const uint4*)(Gsrc + i0 * D + fq * 8);
                uint4 u1 = *(const uint4*)(Gsrc + i1 * D + fq * 8);
                aA0 += bflo(u0.x) + bflo(u1.x);  aA1 += bfhi(u0.x) + bfhi(u1.x);
                aA2 += bflo(u0.y) + bflo(u1.y);  aA3 += bfhi(u0.y) + bfhi(u1.y);
                aA4 += bflo(u0.z) + bflo(u1.z);  aA5 += bfhi(u0.z) + bfhi(u1.z);
                aA6 += bflo(u0.w) + bflo(u1.w);  aA7 += bfhi(u0.w) + bfhi(u1.w);
            }
            for (; b < mA; b += 8) {
                int sidx = b + sub;
                int scl = sidx < mA ? sidx : (mA - 1);
                int i0 = __shfl(pA, scl, 64);
                if (sidx < mA) {
                    uint4 u = *(const uint4*)(Gsrc + i0 * D + fq * 8);
                    aA0 += bflo(u.x); aA1 += bfhi(u.x);
                    aA2 += bflo(u.y); aA3 += bfhi(u.y);
                    aA4 += bflo(u.z); aA5 += bfhi(u.z);
                    aA6 += bflo(u.w); aA7 += bfhi(u.w);
                }
            }
        }
        if (mB) {
            int b = 0;
            for (; b + 16 <= mB; b += 16) {
                int i0 = __shfl(pB, b + sub, 64);
                int i1 = __shfl(pB, b + 8 + sub, 64);
                uint4 u0 = *(const uint4*)(Gsrc + i0 * D + fq * 8);
                uint4 u1 = *(const uint4*)(Gsrc + i1 * D + fq * 8);
                aB0 += bflo(u0.x) + bflo(u1.x);  aB1 += bfhi(u0.x) + bfhi(u1.x);
                aB2 += bflo(u0.y) + bflo(u1.y);  aB3 += bfhi(u0.y) + bfhi(u1.y);
                aB4 += bflo(u0.z) + bflo(u1.z);  aB5 += bfhi(u0.z) + bfhi(u1.z);
                aB6 += bflo(u0.w) + bflo(u1.w);  aB7 += bfhi(u0.w) + bfhi(u1.w);
            }
            for (; b < mB; b += 8) {
                int sidx = b + sub;
                int scl = sidx < mB ? sidx : (mB - 1);
                int i0 = __shfl(pB, scl, 64);
                if (sidx < mB) {
                    uint4 u = *(const uint4*)(Gsrc + i0 * D + fq * 8);
                    aB0 += bflo(u.x); aB1 += bfhi(u.x);
                    aB2 += bflo(u.y); aB3 += bfhi(u.y);
                    aB4 += bflo(u.z); aB5 += bfhi(u.z);
                    aB6 += bflo(u.w); aB7 += bfhi(u.w);
                }
            }
        }
        jbA += 64; jbB += 64;
    }

#pragma unroll
    for (int mk = 8; mk <= 32; mk <<= 1) {
        aA0 += __shfl_xor(aA0, mk, 64); aA1 += __shfl_xor(aA1, mk, 64);
        aA2 += __shfl_xor(aA2, mk, 64); aA3 += __shfl_xor(aA3, mk, 64);
        aA4 += __shfl_xor(aA4, mk, 64); aA5 += __shfl_xor(aA5, mk, 64);
        aA6 += __shfl_xor(aA6, mk, 64); aA7 += __shfl_xor(aA7, mk, 64);
        aB0 += __shfl_xor(aB0, mk, 64); aB1 += __shfl_xor(aB1, mk, 64);
        aB2 += __shfl_xor(aB2, mk, 64); aB3 += __shfl_xor(aB3, mk, 64);
        aB4 += __shfl_xor(aB4, mk, 64); aB5 += __shfl_xor(aB5, mk, 64);
        aB6 += __shfl_xor(aB6, mk, 64); aB7 += __shfl_xor(aB7, mk, 64);
    }
    if (sub == 0) {
        float4 w0, w1;
        w0.x = aA0 + xA0.x + b0.x; w0.y = aA1 + xA0.y + b0.y;
        w0.z = aA2 + xA0.z + b0.z; w0.w = aA3 + xA0.w + b0.w;
        w1.x = aA4 + xA1.x + b1.x; w1.y = aA5 + xA1.y + b1.y;
        w1.z = aA6 + xA1.z + b1.z; w1.w = aA7 + xA1.w + b1.w;
        *(float4*)(outF + (size_t)nA * D + fq * 8) = w0;
        *(float4*)(outF + (size_t)nA * D + fq * 8 + 4) = w1;
        w0.x = aB0 + xB0.x + b0.x; w0.y = aB1 + xB0.y + b0.y;
        w0.z = aB2 + xB0.z + b0.z; w0.w = aB3 + xB0.w + b0.w;
        w1.x = aB4 + xB1.x + b1.x; w1.y = aB5 + xB1.y + b1.y;
        w1.z = aB6 + xB1.z + b1.z; w1.w = aB7 + xB1.w + b1.w;
        *(float4*)(outF + (size_t)nB * D + fq * 8) = w0;
        *(float4*)(outF + (size_t)nB * D + fq * 8 + 4) = w1;
    }
}

// ---------- launch ----------------------------------------------------------
extern "C" void kernel_launch(void* const* d_in, const int* in_sizes, int n_in,
                              void* d_out, int out_size, void* d_ws, size_t ws_size,
                              hipStream_t stream) {
    const float* x   = (const float*)d_in[0];
    const int*   edg = (const int*)d_in[1];
    const float* W1r = (const float*)d_in[2];
    const float* W1n = (const float*)d_in[3];
    const float* b1  = (const float*)d_in[4];
    const float* W2r = (const float*)d_in[5];
    const float* W2n = (const float*)d_in[6];
    const float* b2  = (const float*)d_in[7];
    float* out = (float*)d_out;

    const int* src = edg;
    const int* dst = edg + N_EDGES;

    // ws (256 MiB) — non-overlapping layout.
    int* W              = (int*)d_ws;
    int* cursorPad      = W;                          // NBUCKETS*16 ints
    int* staged         = W + NBUCKETS * 16;          // NBUCKETS*BCAP ints
    int* csr            = staged + NBUCKETS * BCAP;   // NBUCKETS*BCAP ints
    int* startEnd       = csr + NBUCKETS * BCAP;      // N_NODES int2 (packed)
    float* xr           = (float*)(startEnd + 2 * N_NODES); // fp32 [N][64]
    unsigned short* xn  = (unsigned short*)(xr + (size_t)N_NODES * D); // bf16 x@W1n
    float* hr           = (float*)(xn + (size_t)N_NODES * D);          // fp32 h@W2r
    unsigned short* hn  = (unsigned short*)(hr + (size_t)N_NODES * D); // bf16 h@W2n
    unsigned short* wt  = hn + (size_t)N_NODES * D;   // 4x[64][64] bf16 W^T

    // prep: zero cursors + bf16 W^T
    prep_kernel<<<12, 256, 0, stream>>>(W1r, W1n, W2r, W2n, cursorPad, wt);

    // [scatter || layer-1 dual MFMA GEMM]  (xr = x@W1r fp32, xn = x@W1n bf16)
    scatter_gemm1<<<SBLOCKS + MB, 256, 0, stream>>>(
        src, dst, cursorPad, staged, x, wt, xr, xn);

    // fused: build bucket CSR -> h = relu(xr + segsum(xn[src]) + b1)
    //        -> hr = h@W2r, hn = h@W2n
    gather1_gemm2<<<NBUCKETS, 512, 0, stream>>>(
        cursorPad, staged, csr, startEnd, xn, xr, b1, wt, hr, hn);

    // out = hr + segsum(hn[src]) + b2
    gather2_out<<<N_NODES / 8, 256, 0, stream>>>(
        hn, hr, b2, startEnd, csr, out);
}

// Round 11
// 167.715 us; speedup vs baseline: 1.1174x; 1.1174x over previous
//
#include <hip/hip_runtime.h>

#define N_NODES 50000
#define N_EDGES 800000
#define D 64
#define NBUCKETS 782          // dst>>6, 0..781
#define NPB 64                // nodes per bucket
#define BCAP 2048             // per-bucket capacity (Poisson(1024), huge margin)
#define SBLOCKS 256           // scatter blocks
#define CHUNK (N_EDGES / SBLOCKS)   // 3125
#define MB ((N_NODES + 63) / 64)    // 782 gemm tiles

typedef short bf16x8 __attribute__((ext_vector_type(8)));   // 8 bf16 = 4 VGPRs
typedef float f32x4  __attribute__((ext_vector_type(4)));   // MFMA accumulator

// bf16 helpers (RNE), bit-level.
__device__ __forceinline__ unsigned short f2bf(float f) {
    unsigned u = __float_as_uint(f);
    return (unsigned short)((u + 0x7fffu + ((u >> 16) & 1u)) >> 16);
}
__device__ __forceinline__ float bflo(unsigned u) {
    return __uint_as_float(u << 16);
}
__device__ __forceinline__ float bfhi(unsigned u) {
    return __uint_as_float(u & 0xffff0000u);
}

// ---------- prep: zero cursors + build bf16 W^T for all 4 weights -----------
__global__ void __launch_bounds__(256) prep_kernel(
    const float* __restrict__ W1r, const float* __restrict__ W1n,
    const float* __restrict__ W2r, const float* __restrict__ W2n,
    int* __restrict__ cursorPad, unsigned short* __restrict__ wt) {
    int t = threadIdx.x;
    if (blockIdx.x == 4) {
        for (int i = t; i < NBUCKETS * 16; i += 256) cursorPad[i] = 0;
        return;
    }
    const float* Wsrc = blockIdx.x == 0 ? W1r : blockIdx.x == 1 ? W1n
                      : blockIdx.x == 2 ? W2r : W2n;
    unsigned short* dstw = wt + blockIdx.x * D * D;
    for (int i = t; i < D * D; i += 256) {
        int k = i >> 6, c = i & 63;           // coalesced read of W[k][c]
        dstw[c * D + k] = f2bf(Wsrc[i]);      // transposed bf16 store
    }
}

// ---------- scatter body (verified R3 two-pass form; fine buckets) ----------
__device__ __forceinline__ void scatter_body(
    const int* __restrict__ src, const int* __restrict__ dst,
    int* __restrict__ cursorPad, int* __restrict__ staged,
    char* smem, int bid, int t) {
    int* hist = (int*)smem;
    int* curs = (int*)(smem + 3200);
    int* pk   = (int*)(smem + 6400);
    unsigned short* bk = (unsigned short*)(smem + 6400 + 12500);
    for (int i = t; i < NBUCKETS; i += 256) hist[i] = 0;
    __syncthreads();
    int lo = bid * CHUNK;
    for (int i = t; i < CHUNK; i += 256) {
        int d = dst[lo + i];
        int s = src[lo + i];
        pk[i] = (s << 6) | (d & 63);
        bk[i] = (unsigned short)(d >> 6);
        atomicAdd(&hist[d >> 6], 1);
    }
    __syncthreads();
    for (int k = t; k < NBUCKETS; k += 256)
        if (hist[k] > 0)
            curs[k] = k * BCAP + atomicAdd(&cursorPad[k * 16], hist[k]);
    __syncthreads();
    for (int i = t; i < CHUNK; i += 256) {
        int b = bk[i];
        int pos = atomicAdd(&curs[b], 1);
        staged[pos] = pk[i];
    }
}

// ---------- MFMA dual GEMM body (verified R7 form) --------------------------
template<int XBF>
__device__ __forceinline__ void gemm_mfma_body(
    const float* __restrict__ Xf, const unsigned short* __restrict__ Xb,
    const unsigned short* __restrict__ Wtr, const unsigned short* __restrict__ Wtn,
    float* __restrict__ outR, unsigned short* __restrict__ outN,
    int node0, int tid) {
    int wave = tid >> 6, lane = tid & 63;
    int rbase = node0 + wave * 16;            // 16 nodes per wave
    int rrow  = lane & 15;
    int kg    = lane >> 4;                    // k-chunk selector (0..3)
    int row   = min(rbase + rrow, N_NODES - 1);

    bf16x8 a0, a1;                            // k 0..31 / 32..63
    if (XBF) {
        a0 = *(const bf16x8*)(Xb + (size_t)row * D + kg * 8);
        a1 = *(const bf16x8*)(Xb + (size_t)row * D + 32 + kg * 8);
    } else {
        const float* xp = Xf + (size_t)row * D + kg * 8;
#pragma unroll
        for (int j = 0; j < 8; j++) a0[j] = (short)f2bf(xp[j]);
#pragma unroll
        for (int j = 0; j < 8; j++) a1[j] = (short)f2bf(xp[32 + j]);
    }

    f32x4 accR[4], accN[4];
#pragma unroll
    for (int t = 0; t < 4; t++) {
        accR[t][0] = 0.f; accR[t][1] = 0.f; accR[t][2] = 0.f; accR[t][3] = 0.f;
        accN[t][0] = 0.f; accN[t][1] = 0.f; accN[t][2] = 0.f; accN[t][3] = 0.f;
    }

#pragma unroll
    for (int t = 0; t < 4; t++) {
        int c = t * 16 + rrow;                // W^T row = W column
        bf16x8 br0 = *(const bf16x8*)(Wtr + c * D + kg * 8);
        bf16x8 br1 = *(const bf16x8*)(Wtr + c * D + 32 + kg * 8);
        bf16x8 bn0 = *(const bf16x8*)(Wtn + c * D + kg * 8);
        bf16x8 bn1 = *(const bf16x8*)(Wtn + c * D + 32 + kg * 8);
        accR[t] = __builtin_amdgcn_mfma_f32_16x16x32_bf16(a0, br0, accR[t], 0, 0, 0);
        accR[t] = __builtin_amdgcn_mfma_f32_16x16x32_bf16(a1, br1, accR[t], 0, 0, 0);
        accN[t] = __builtin_amdgcn_mfma_f32_16x16x32_bf16(a0, bn0, accN[t], 0, 0, 0);
        accN[t] = __builtin_amdgcn_mfma_f32_16x16x32_bf16(a1, bn1, accN[t], 0, 0, 0);
    }

#pragma unroll
    for (int t = 0; t < 4; t++) {
#pragma unroll
        for (int i = 0; i < 4; i++) {
            int n = rbase + kg * 4 + i;       // D row
            if (n < N_NODES) {
                int c = t * 16 + rrow;        // D col
                outR[(size_t)n * D + c] = accR[t][i];
                outN[(size_t)n * D + c] = f2bf(accN[t][i]);
            }
        }
    }
}

// ---------- merged scatter + layer-1 GEMM (block-specialized) ---------------
__global__ void __launch_bounds__(256) scatter_gemm1(
    const int* __restrict__ src, const int* __restrict__ dst,
    int* __restrict__ cursorPad, int* __restrict__ staged,
    const float* __restrict__ X, const unsigned short* __restrict__ wt,
    float* __restrict__ xr, unsigned short* __restrict__ xn) {
    __shared__ char smem[25600];              // scatter role only
    if (blockIdx.x < SBLOCKS) {
        scatter_body(src, dst, cursorPad, staged, smem, blockIdx.x, threadIdx.x);
    } else {
        gemm_mfma_body<0>(X, (const unsigned short*)0,
                          wt + 0 * D * D, wt + 1 * D * D,
                          xr, xn, (blockIdx.x - SBLOCKS) * 64, threadIdx.x);
    }
}

// ---------- per-bucket CSR build (R6 form; packed startEnd int2) ------------
__global__ void __launch_bounds__(256) csr_build_kernel(
    const int* __restrict__ cursorPad, const int* __restrict__ staged,
    int* __restrict__ csr, int* __restrict__ startEnd) {
    __shared__ int deg[NPB];
    __shared__ int sc[NPB];
    __shared__ int curs[NPB];
    __shared__ int lcsr[BCAP];
    int k = blockIdx.x;
    int t = threadIdx.x;
    int base = k * BCAP;
    int cnt  = cursorPad[k * 16];
    if (t < NPB) deg[t] = 0;
    __syncthreads();
    for (int i = t; i < cnt; i += 256)
        atomicAdd(&deg[staged[base + i] & 63], 1);
    __syncthreads();
    int v = (t < NPB) ? deg[t] : 0;
    if (t < NPB) sc[t] = v;
    __syncthreads();
#pragma unroll
    for (int d = 1; d < NPB; d <<= 1) {
        int u = (t < NPB && t >= d) ? sc[t - d] : 0;
        __syncthreads();
        if (t < NPB) sc[t] += u;
        __syncthreads();
    }
    if (t < NPB) {
        int start = sc[t] - v;
        int node = k * NPB + t;
        if (node < N_NODES) {
            int2 se; se.x = base + start; se.y = base + start + v;
            ((int2*)startEnd)[node] = se;          // packed {start,end}
        }
        curs[t] = start;
    }
    __syncthreads();
    for (int i = t; i < cnt; i += 256) {
        int e = staged[base + i];
        int pos = atomicAdd(&curs[e & 63], 1);
        lcsr[pos] = e >> 6;
    }
    __syncthreads();
    for (int i = t; i < cnt; i += 256)
        csr[base + i] = lcsr[i];
}

// ---------- fused layer-1 gather + layer-2 GEMM -----------------------------
// 512 threads = 8 waves x 2 nodes = 16 nodes/block (50000 = 3125 x 16 exact).
// Phase A: R8-verified 2-node gather body; epilogue writes relu'd h (bf16)
// into a padded LDS tile instead of global hbf.
// Phase B: dual MFMA GEMM (R7-verified fragment mapping); wave w handles
// column-tile (w>>1) for output kind (w&1): 0 -> hr fp32, 1 -> hn bf16.
__global__ void __launch_bounds__(512) gather1_gemm2(
    const unsigned short* __restrict__ Gsrc, const float* __restrict__ Root,
    const float* __restrict__ bias,
    const int* __restrict__ startEnd, const int* __restrict__ csr,
    const unsigned short* __restrict__ wt,
    float* __restrict__ hr, unsigned short* __restrict__ hn) {
    __shared__ unsigned short hlds[16][72];   // 16 h rows, pitch 72 (2-way banks)
    int tid = threadIdx.x;
    int wave = tid >> 6, lane = tid & 63;
    int n0 = blockIdx.x * 16;
    int nA = n0 + wave * 2;
    int nB = nA + 1;
    int sub = lane >> 3, fq = lane & 7;

    int4 se = *(const int4*)(startEnd + nA * 2);
    int jbA = se.x, jeA = se.y, jbB = se.z, jeB = se.w;

    float4 xA0, xA1, xB0, xB1, b0, b1;
    if (sub == 0) {
        const float* rpA = Root + (size_t)nA * D + fq * 8;
        const float* rpB = Root + (size_t)nB * D + fq * 8;
        xA0 = *(const float4*)rpA; xA1 = *(const float4*)(rpA + 4);
        xB0 = *(const float4*)rpB; xB1 = *(const float4*)(rpB + 4);
        b0 = ((const float4*)bias)[fq * 2];
        b1 = ((const float4*)bias)[fq * 2 + 1];
    }

    float aA0=0.f,aA1=0.f,aA2=0.f,aA3=0.f,aA4=0.f,aA5=0.f,aA6=0.f,aA7=0.f;
    float aB0=0.f,aB1=0.f,aB2=0.f,aB3=0.f,aB4=0.f,aB5=0.f,aB6=0.f,aB7=0.f;

    while (jbA < jeA || jbB < jeB) {          // wave-uniform
        int pA = 0, pB = 0, mA = 0, mB = 0;
        if (jbA < jeA) {
            int idx = jbA + lane;
            pA = csr[idx < jeA ? idx : (jeA - 1)];
            mA = min(64, jeA - jbA);
        }
        if (jbB < jeB) {
            int idx = jbB + lane;
            pB = csr[idx < jeB ? idx : (jeB - 1)];
            mB = min(64, jeB - jbB);
        }
        if (mA) {
            int b = 0;
            for (; b + 16 <= mA; b += 16) {
                int i0 = __shfl(pA, b + sub, 64);
                int i1 = __shfl(pA, b + 8 + sub, 64);
                uint4 u0 = *(const uint4*)(Gsrc + i0 * D + fq * 8);
                uint4 u1 = *(const uint4*)(Gsrc + i1 * D + fq * 8);
                aA0 += bflo(u0.x) + bflo(u1.x);  aA1 += bfhi(u0.x) + bfhi(u1.x);
                aA2 += bflo(u0.y) + bflo(u1.y);  aA3 += bfhi(u0.y) + bfhi(u1.y);
                aA4 += bflo(u0.z) + bflo(u1.z);  aA5 += bfhi(u0.z) + bfhi(u1.z);
                aA6 += bflo(u0.w) + bflo(u1.w);  aA7 += bfhi(u0.w) + bfhi(u1.w);
            }
            for (; b < mA; b += 8) {
                int sidx = b + sub;
                int scl = sidx < mA ? sidx : (mA - 1);
                int i0 = __shfl(pA, scl, 64);
                if (sidx < mA) {
                    uint4 u = *(const uint4*)(Gsrc + i0 * D + fq * 8);
                    aA0 += bflo(u.x); aA1 += bfhi(u.x);
                    aA2 += bflo(u.y); aA3 += bfhi(u.y);
                    aA4 += bflo(u.z); aA5 += bfhi(u.z);
                    aA6 += bflo(u.w); aA7 += bfhi(u.w);
                }
            }
        }
        if (mB) {
            int b = 0;
            for (; b + 16 <= mB; b += 16) {
                int i0 = __shfl(pB, b + sub, 64);
                int i1 = __shfl(pB, b + 8 + sub, 64);
                uint4 u0 = *(const uint4*)(Gsrc + i0 * D + fq * 8);
                uint4 u1 = *(const uint4*)(Gsrc + i1 * D + fq * 8);
                aB0 += bflo(u0.x) + bflo(u1.x);  aB1 += bfhi(u0.x) + bfhi(u1.x);
                aB2 += bflo(u0.y) + bflo(u1.y);  aB3 += bfhi(u0.y) + bfhi(u1.y);
                aB4 += bflo(u0.z) + bflo(u1.z);  aB5 += bfhi(u0.z) + bfhi(u1.z);
                aB6 += bflo(u0.w) + bflo(u1.w);  aB7 += bfhi(u0.w) + bfhi(u1.w);
            }
            for (; b < mB; b += 8) {
                int sidx = b + sub;
                int scl = sidx < mB ? sidx : (mB - 1);
                int i0 = __shfl(pB, scl, 64);
                if (sidx < mB) {
                    uint4 u = *(const uint4*)(Gsrc + i0 * D + fq * 8);
                    aB0 += bflo(u.x); aB1 += bfhi(u.x);
                    aB2 += bflo(u.y); aB3 += bfhi(u.y);
                    aB4 += bflo(u.z); aB5 += bfhi(u.z);
                    aB6 += bflo(u.w); aB7 += bfhi(u.w);
                }
            }
        }
        jbA += 64; jbB += 64;
    }

#pragma unroll
    for (int mk = 8; mk <= 32; mk <<= 1) {
        aA0 += __shfl_xor(aA0, mk, 64); aA1 += __shfl_xor(aA1, mk, 64);
        aA2 += __shfl_xor(aA2, mk, 64); aA3 += __shfl_xor(aA3, mk, 64);
        aA4 += __shfl_xor(aA4, mk, 64); aA5 += __shfl_xor(aA5, mk, 64);
        aA6 += __shfl_xor(aA6, mk, 64); aA7 += __shfl_xor(aA7, mk, 64);
        aB0 += __shfl_xor(aB0, mk, 64); aB1 += __shfl_xor(aB1, mk, 64);
        aB2 += __shfl_xor(aB2, mk, 64); aB3 += __shfl_xor(aB3, mk, 64);
        aB4 += __shfl_xor(aB4, mk, 64); aB5 += __shfl_xor(aB5, mk, 64);
        aB6 += __shfl_xor(aB6, mk, 64); aB7 += __shfl_xor(aB7, mk, 64);
    }
    if (sub == 0) {
        float r0 = fmaxf(aA0 + xA0.x + b0.x, 0.f), r1 = fmaxf(aA1 + xA0.y + b0.y, 0.f);
        float r2 = fmaxf(aA2 + xA0.z + b0.z, 0.f), r3 = fmaxf(aA3 + xA0.w + b0.w, 0.f);
        float r4 = fmaxf(aA4 + xA1.x + b1.x, 0.f), r5 = fmaxf(aA5 + xA1.y + b1.y, 0.f);
        float r6 = fmaxf(aA6 + xA1.z + b1.z, 0.f), r7 = fmaxf(aA7 + xA1.w + b1.w, 0.f);
        float s0 = fmaxf(aB0 + xB0.x + b0.x, 0.f), s1 = fmaxf(aB1 + xB0.y + b0.y, 0.f);
        float s2 = fmaxf(aB2 + xB0.z + b0.z, 0.f), s3 = fmaxf(aB3 + xB0.w + b0.w, 0.f);
        float s4 = fmaxf(aB4 + xB1.x + b1.x, 0.f), s5 = fmaxf(aB5 + xB1.y + b1.y, 0.f);
        float s6 = fmaxf(aB6 + xB1.z + b1.z, 0.f), s7 = fmaxf(aB7 + xB1.w + b1.w, 0.f);
        uint4 u;
        u.x = (unsigned)f2bf(r0) | ((unsigned)f2bf(r1) << 16);
        u.y = (unsigned)f2bf(r2) | ((unsigned)f2bf(r3) << 16);
        u.z = (unsigned)f2bf(r4) | ((unsigned)f2bf(r5) << 16);
        u.w = (unsigned)f2bf(r6) | ((unsigned)f2bf(r7) << 16);
        *(uint4*)&hlds[wave * 2][fq * 8] = u;       // pitch 144B, 16B aligned
        u.x = (unsigned)f2bf(s0) | ((unsigned)f2bf(s1) << 16);
        u.y = (unsigned)f2bf(s2) | ((unsigned)f2bf(s3) << 16);
        u.z = (unsigned)f2bf(s4) | ((unsigned)f2bf(s5) << 16);
        u.w = (unsigned)f2bf(s6) | ((unsigned)f2bf(s7) << 16);
        *(uint4*)&hlds[wave * 2 + 1][fq * 8] = u;
    }
    __syncthreads();

    // ---- phase B: dual GEMM over the block's 16 h rows
    int t4   = wave >> 1;                     // column tile 0..3
    int kind = wave & 1;                      // 0 -> hr (fp32), 1 -> hn (bf16)
    int rrow = lane & 15;
    int kg   = lane >> 4;
    bf16x8 a0 = *(const bf16x8*)&hlds[rrow][kg * 8];
    bf16x8 a1 = *(const bf16x8*)&hlds[rrow][32 + kg * 8];
    const unsigned short* Wt = wt + (2 + kind) * D * D;
    int c = t4 * 16 + rrow;
    bf16x8 bw0 = *(const bf16x8*)(Wt + c * D + kg * 8);
    bf16x8 bw1 = *(const bf16x8*)(Wt + c * D + 32 + kg * 8);
    f32x4 acc;
    acc[0] = 0.f; acc[1] = 0.f; acc[2] = 0.f; acc[3] = 0.f;
    acc = __builtin_amdgcn_mfma_f32_16x16x32_bf16(a0, bw0, acc, 0, 0, 0);
    acc = __builtin_amdgcn_mfma_f32_16x16x32_bf16(a1, bw1, acc, 0, 0, 0);
    if (kind == 0) {
#pragma unroll
        for (int i = 0; i < 4; i++)
            hr[(size_t)(n0 + kg * 4 + i) * D + c] = acc[i];
    } else {
#pragma unroll
        for (int i = 0; i < 4; i++)
            hn[(size_t)(n0 + kg * 4 + i) * D + c] = f2bf(acc[i]);
    }
}

// ---------- Gather 2 (verified R8 2-node form) + final epilogue -------------
__global__ void __launch_bounds__(256) gather2_out(
    const unsigned short* __restrict__ Gsrc, const float* __restrict__ Root,
    const float* __restrict__ bias,
    const int* __restrict__ startEnd, const int* __restrict__ csr,
    float* __restrict__ outF) {
    int tid = threadIdx.x;
    int wave = tid >> 6, lane = tid & 63;
    int nA = blockIdx.x * 8 + wave * 2;
    int nB = nA + 1;
    int sub = lane >> 3, fq = lane & 7;

    int4 se = *(const int4*)(startEnd + nA * 2);
    int jbA = se.x, jeA = se.y, jbB = se.z, jeB = se.w;

    float4 xA0, xA1, xB0, xB1, b0, b1;
    if (sub == 0) {
        const float* rpA = Root + (size_t)nA * D + fq * 8;
        const float* rpB = Root + (size_t)nB * D + fq * 8;
        xA0 = *(const float4*)rpA; xA1 = *(const float4*)(rpA + 4);
        xB0 = *(const float4*)rpB; xB1 = *(const float4*)(rpB + 4);
        b0 = ((const float4*)bias)[fq * 2];
        b1 = ((const float4*)bias)[fq * 2 + 1];
    }

    float aA0=0.f,aA1=0.f,aA2=0.f,aA3=0.f,aA4=0.f,aA5=0.f,aA6=0.f,aA7=0.f;
    float aB0=0.f,aB1=0.f,aB2=0.f,aB3=0.f,aB4=0.f,aB5=0.f,aB6=0.f,aB7=0.f;

    while (jbA < jeA || jbB < jeB) {
        int pA = 0, pB = 0, mA = 0, mB = 0;
        if (jbA < jeA) {
            int idx = jbA + lane;
            pA = csr[idx < jeA ? idx : (jeA - 1)];
            mA = min(64, jeA - jbA);
        }
        if (jbB < jeB) {
            int idx = jbB + lane;
            pB = csr[idx < jeB ? idx : (jeB - 1)];
            mB = min(64, jeB - jbB);
        }
        if (mA) {
            int b = 0;
            for (; b + 16 <= mA; b += 16) {
                int i0 = __shfl(pA, b + sub, 64);
                int i1 = __shfl(pA, b + 8 + sub, 64);
                uint4 u0 = *(const uint4*)(Gsrc + i0 * D + fq * 8);
                uint4 u1 = *(const uint4*)(Gsrc + i1 * D + fq * 8);
                aA0 += bflo(u0.x) + bflo(u1.x);  aA1 += bfhi(u0.x) + bfhi(u1.x);
                aA2 += bflo(u0.y) + bflo(u1.y);  aA3 += bfhi(u0.y) + bfhi(u1.y);
                aA4 += bflo(u0.z) + bflo(u1.z);  aA5 += bfhi(u0.z) + bfhi(u1.z);
                aA6 += bflo(u0.w) + bflo(u1.w);  aA7 += bfhi(u0.w) + bfhi(u1.w);
            }
            for (; b < mA; b += 8) {
                int sidx = b + sub;
                int scl = sidx < mA ? sidx : (mA - 1);
                int i0 = __shfl(pA, scl, 64);
                if (sidx < mA) {
                    uint4 u = *(const uint4*)(Gsrc + i0 * D + fq * 8);
                    aA0 += bflo(u.x); aA1 += bfhi(u.x);
                    aA2 += bflo(u.y); aA3 += bfhi(u.y);
                    aA4 += bflo(u.z); aA5 += bfhi(u.z);
                    aA6 += bflo(u.w); aA7 += bfhi(u.w);
                }
            }
        }
        if (mB) {
            int b = 0;
            for (; b + 16 <= mB; b += 16) {
                int i0 = __shfl(pB, b + sub, 64);
                int i1 = __shfl(pB, b + 8 + sub, 64);
                uint4 u0 = *(const uint4*)(Gsrc + i0 * D + fq * 8);
                uint4 u1 = *(const uint4*)(Gsrc + i1 * D + fq * 8);
                aB0 += bflo(u0.x) + bflo(u1.x);  aB1 += bfhi(u0.x) + bfhi(u1.x);
                aB2 += bflo(u0.y) + bflo(u1.y);  aB3 += bfhi(u0.y) + bfhi(u1.y);
                aB4 += bflo(u0.z) + bflo(u1.z);  aB5 += bfhi(u0.z) + bfhi(u1.z);
                aB6 += bflo(u0.w) + bflo(u1.w);  aB7 += bfhi(u0.w) + bfhi(u1.w);
            }
            for (; b < mB; b += 8) {
                int sidx = b + sub;
                int scl = sidx < mB ? sidx : (mB - 1);
                int i0 = __shfl(pB, scl, 64);
                if (sidx < mB) {
                    uint4 u = *(const uint4*)(Gsrc + i0 * D + fq * 8);
                    aB0 += bflo(u.x); aB1 += bfhi(u.x);
                    aB2 += bflo(u.y); aB3 += bfhi(u.y);
                    aB4 += bflo(u.z); aB5 += bfhi(u.z);
                    aB6 += bflo(u.w); aB7 += bfhi(u.w);
                }
            }
        }
        jbA += 64; jbB += 64;
    }

#pragma unroll
    for (int mk = 8; mk <= 32; mk <<= 1) {
        aA0 += __shfl_xor(aA0, mk, 64); aA1 += __shfl_xor(aA1, mk, 64);
        aA2 += __shfl_xor(aA2, mk, 64); aA3 += __shfl_xor(aA3, mk, 64);
        aA4 += __shfl_xor(aA4, mk, 64); aA5 += __shfl_xor(aA5, mk, 64);
        aA6 += __shfl_xor(aA6, mk, 64); aA7 += __shfl_xor(aA7, mk, 64);
        aB0 += __shfl_xor(aB0, mk, 64); aB1 += __shfl_xor(aB1, mk, 64);
        aB2 += __shfl_xor(aB2, mk, 64); aB3 += __shfl_xor(aB3, mk, 64);
        aB4 += __shfl_xor(aB4, mk, 64); aB5 += __shfl_xor(aB5, mk, 64);
        aB6 += __shfl_xor(aB6, mk, 64); aB7 += __shfl_xor(aB7, mk, 64);
    }
    if (sub == 0) {
        float4 w0, w1;
        w0.x = aA0 + xA0.x + b0.x; w0.y = aA1 + xA0.y + b0.y;
        w0.z = aA2 + xA0.z + b0.z; w0.w = aA3 + xA0.w + b0.w;
        w1.x = aA4 + xA1.x + b1.x; w1.y = aA5 + xA1.y + b1.y;
        w1.z = aA6 + xA1.z + b1.z; w1.w = aA7 + xA1.w + b1.w;
        *(float4*)(outF + (size_t)nA * D + fq * 8) = w0;
        *(float4*)(outF + (size_t)nA * D + fq * 8 + 4) = w1;
        w0.x = aB0 + xB0.x + b0.x; w0.y = aB1 + xB0.y + b0.y;
        w0.z = aB2 + xB0.z + b0.z; w0.w = aB3 + xB0.w + b0.w;
        w1.x = aB4 + xB1.x + b1.x; w1.y = aB5 + xB1.y + b1.y;
        w1.z = aB6 + xB1.z + b1.z; w1.w = aB7 + xB1.w + b1.w;
        *(float4*)(outF + (size_t)nB * D + fq * 8) = w0;
        *(float4*)(outF + (size_t)nB * D + fq * 8 + 4) = w1;
    }
}

// ---------- launch ----------------------------------------------------------
extern "C" void kernel_launch(void* const* d_in, const int* in_sizes, int n_in,
                              void* d_out, int out_size, void* d_ws, size_t ws_size,
                              hipStream_t stream) {
    const float* x   = (const float*)d_in[0];
    const int*   edg = (const int*)d_in[1];
    const float* W1r = (const float*)d_in[2];
    const float* W1n = (const float*)d_in[3];
    const float* b1  = (const float*)d_in[4];
    const float* W2r = (const float*)d_in[5];
    const float* W2n = (const float*)d_in[6];
    const float* b2  = (const float*)d_in[7];
    float* out = (float*)d_out;

    const int* src = edg;
    const int* dst = edg + N_EDGES;

    // ws (256 MiB) — non-overlapping layout (hbf eliminated).
    int* W              = (int*)d_ws;
    int* cursorPad      = W;                          // NBUCKETS*16 ints
    int* staged         = W + NBUCKETS * 16;          // NBUCKETS*BCAP ints
    int* csr            = staged + NBUCKETS * BCAP;   // NBUCKETS*BCAP ints
    int* startEnd       = csr + NBUCKETS * BCAP;      // N_NODES int2 (packed)
    float* xr           = (float*)(startEnd + 2 * N_NODES); // fp32 [N][64]
    unsigned short* xn  = (unsigned short*)(xr + (size_t)N_NODES * D); // bf16 x@W1n
    float* hr           = (float*)(xn + (size_t)N_NODES * D);          // fp32 h@W2r
    unsigned short* hn  = (unsigned short*)(hr + (size_t)N_NODES * D); // bf16 h@W2n
    unsigned short* wt  = hn + (size_t)N_NODES * D;   // 4x[64][64] bf16 W^T

    // prep: zero cursors + bf16 W^T
    prep_kernel<<<5, 256, 0, stream>>>(W1r, W1n, W2r, W2n, cursorPad, wt);

    // [scatter || layer-1 dual MFMA GEMM]  (xr = x@W1r fp32, xn = x@W1n bf16)
    scatter_gemm1<<<SBLOCKS + MB, 256, 0, stream>>>(
        src, dst, cursorPad, staged, x, wt, xr, xn);

    csr_build_kernel<<<NBUCKETS, 256, 0, stream>>>(cursorPad, staged, csr,
                                                   startEnd);

    // fused: h = relu(xr + segsum(xn[src]) + b1)  ->  hr = h@W2r, hn = h@W2n
    gather1_gemm2<<<N_NODES / 16, 512, 0, stream>>>(
        xn, xr, b1, startEnd, csr, wt, hr, hn);

    // out = hr + segsum(hn[src]) + b2
    gather2_out<<<N_NODES / 8, 256, 0, stream>>>(
        hn, hr, b2, startEnd, csr, out);
}